// Round 6
// baseline (134.231 us; speedup 1.0000x reference)
//
#include <hip/hip_runtime.h>
#include <stdint.h>

#define KD 256
#define NO 256
#define NE 16
#define BM 64
#define BN 128
#define XROW 264        // X stage row stride (shorts): 256 + 8 pad
#define GROW 68         // gate_t row stride (floats): 16B-aligned quads
#define NFRAG 128       // NE * (KD/32) fragment-sets of K=32

typedef short bf16x8 __attribute__((ext_vector_type(8)));
typedef float f32x4 __attribute__((ext_vector_type(4)));

__device__ __forceinline__ unsigned short f2bf(float f) {
  uint32_t u = __float_as_uint(f);
  u += 0x7fffu + ((u >> 16) & 1u);   // RNE (finite inputs)
  return (unsigned short)(u >> 16);
}
__device__ __forceinline__ float bf2f(unsigned short h) {
  return __uint_as_float(((uint32_t)h) << 16);
}
// gelu(h) = h * sigmoid(h*(1.5957691 + 0.0713548 h^2))  (tanh form; max err ~1e-4 abs)
__device__ __forceinline__ float gelu_f(float h) {
  float z = h * fmaf(0.07135481627f, h * h, 1.5957691216f);
  return h * __builtin_amdgcn_rcpf(1.0f + __expf(-z));
}

// ---- prep: We[e][d][o] -> Wf fragment-ordered bf16; Wg[d][e] -> Wgt[e][d] bf16 ----
// Wf layout: [e][kc(0..7)][ob(0..15)][lane(0..63)][i(0..7)] bf16, element =
// We[e][ kc*32 + (lane>>4)*8 + i ][ ob*16 + (lane&15) ].  (UNCHANGED — proven)
__global__ void moe_prep(const float* __restrict__ We, unsigned short* __restrict__ Wf,
                         const float* __restrict__ Wg, unsigned short* __restrict__ Wgt)
{
  __shared__ float ts[256 * 17];  // [d][o] tile, padded
  const int tid = threadIdx.x;
  const int bid = blockIdx.x;
  if (bid < 256) {
    const int e = bid >> 4, ob = bid & 15;
    const float* src = We + (size_t)e * KD * NO + ob * 16;
    const int o = tid & 15, dg = tid >> 4;
#pragma unroll
    for (int p = 0; p < 16; ++p) {
      int d = p * 16 + dg;
      ts[d * 17 + o] = src[(size_t)d * NO + o];
    }
    __syncthreads();
    const int w = tid >> 6, l = tid & 63;
    const int q = l >> 4, ln = l & 15;
#pragma unroll
    for (int kk = 0; kk < 2; ++kk) {
      int kc = w + kk * 4;
      unsigned int pk[4];
#pragma unroll
      for (int h = 0; h < 4; ++h) {
        unsigned short lo = f2bf(ts[(kc * 32 + q * 8 + h * 2 + 0) * 17 + ln]);
        unsigned short hi = f2bf(ts[(kc * 32 + q * 8 + h * 2 + 1) * 17 + ln]);
        pk[h] = (unsigned int)lo | ((unsigned int)hi << 16);
      }
      uint4* dst = (uint4*)(Wf + ((((size_t)(e * 8 + kc) * 16 + ob) * 64) + l) * 8);
      *dst = make_uint4(pk[0], pk[1], pk[2], pk[3]);
    }
  } else {
    int d = tid;
    const float* wr = Wg + (size_t)d * NE;
#pragma unroll
    for (int e = 0; e < NE; ++e)
      Wgt[e * KD + d] = f2bf(wr[e]);
  }
}

// ---- main: 1m x 4n waves, A register-resident, depth-8 B ring, expert rotation ----
__launch_bounds__(256, 2)
__global__ void moe_main(const float* __restrict__ x,
                         const uint4* __restrict__ Wf,
                         const unsigned short* __restrict__ Wgt,
                         const float* __restrict__ be,
                         const float* __restrict__ bg,
                         float* __restrict__ out)
{
  __shared__ __align__(16) unsigned short Xs[BM * XROW];  // 33792 B
  __shared__ __align__(16) float gate_t[NE * GROW];        // 4352 B
  __shared__ unsigned short be_h[NE * BN];                 // 4096 B

  const int tid = threadIdx.x;
  const int bid = blockIdx.x;
  const int half = bid & 1;
  const int n0 = half * BN;
  const int m0 = (bid >> 1) * BM;
  const int w = tid >> 6, lane = tid & 63;   // wave w owns cols w*32..w*32+31 (disjoint B)
  const int ln = lane & 15, quad = lane >> 4;
  const int r0 = (bid * 5) & 15;             // per-block expert rotation (phase stagger)

  // per-wave fragment offset (uint4 units); frag j at +j*64 (=1024 B imm)
  const int voff = (half * 8 + w * 2) * 64 + lane;

  // ---- stage X tile fp32 -> bf16
  {
    const float4* xg = (const float4*)x + (size_t)m0 * (KD / 4);
#pragma unroll
    for (int p = 0; p < 16; ++p) {
      int idx = p * 256 + tid;
      int r = idx >> 6, c = idx & 63;
      float4 v = xg[r * (KD / 4) + c];
      uint32_t lo = (uint32_t)f2bf(v.x) | ((uint32_t)f2bf(v.y) << 16);
      uint32_t hi = (uint32_t)f2bf(v.z) | ((uint32_t)f2bf(v.w) << 16);
      *(uint2*)&Xs[r * XROW + c * 4] = make_uint2(lo, hi);
    }
  }
  // ---- ring fill: 8 sets of rotated expert sequence (16 KB in flight during gate)
  uint4 b[8][2];
#pragma unroll
  for (int kc = 0; kc < 8; ++kc) {
    const uint4* p = Wf + (size_t)(r0 * 8 + kc) * 1024 + voff;
    b[kc][0] = p[0]; b[kc][1] = p[64];
  }
  // ---- stage bias (bf16; |be|<=1/16 -> error ~1e-4)
#pragma unroll
  for (int p = 0; p < 8; ++p) {
    int idx = p * 256 + tid;
    int e = idx >> 7, c = idx & 127;
    be_h[e * BN + c] = f2bf(be[e * NO + n0 + c]);
  }
  __syncthreads();

  // ---- A fragments, FULL tile (64 rows x K=256): 32 frags = 128 VGPR, loaded ONCE
  bf16x8 a[4][8];
#pragma unroll
  for (int i = 0; i < 4; ++i)
#pragma unroll
    for (int kc = 0; kc < 8; ++kc)
      a[i][kc] = *(const bf16x8*)&Xs[(i * 16 + ln) * XROW + kc * 32 + quad * 8];

  // ---- gate: wave w computes rows w*16..w*16+15 for all 16 experts (lane ln = expert)
  {
    f32x4 g = {0.f, 0.f, 0.f, 0.f};
#pragma unroll
    for (int kc = 0; kc < 8; ++kc) {
      bf16x8 af = *(const bf16x8*)&Xs[(w * 16 + ln) * XROW + kc * 32 + quad * 8];
      bf16x8 wb = *(const bf16x8*)(Wgt + (size_t)ln * KD + kc * 32 + quad * 8);
      g = __builtin_amdgcn_mfma_f32_16x16x32_bf16(af, wb, g, 0, 0, 0);
    }
    float bgl = bg[ln];
#pragma unroll
    for (int r = 0; r < 4; ++r) {
      float v = g[r] + bgl;
      float mx = v;
#pragma unroll
      for (int msk = 1; msk < 16; msk <<= 1)
        mx = fmaxf(mx, __shfl_xor(mx, msk, 64));
      float ev = __expf(v - mx);
      float s = ev;
#pragma unroll
      for (int msk = 1; msk < 16; msk <<= 1)
        s += __shfl_xor(s, msk, 64);
      gate_t[ln * GROW + w * 16 + quad * 4 + r] = ev * __builtin_amdgcn_rcpf(s);
    }
  }
  __syncthreads();  // gate_t visible; last barrier in the kernel

  f32x4 acc[4][2], oacc[4][2];
#pragma unroll
  for (int i = 0; i < 4; ++i)
#pragma unroll
    for (int j = 0; j < 2; ++j)
      oacc[i][j] = (f32x4){0.f, 0.f, 0.f, 0.f};

#pragma unroll 1
  for (int ei = 0; ei < NE; ++ei) {
    const int e = (ei + r0) & 15;
    const int en = (ei + 1 + r0) & 15;       // next expert (for refills)
    // bias for this expert's two column groups (C-operand init)
    const float bb0 = bf2f(be_h[e * BN + w * 32 + ln]);
    const float bb1 = bf2f(be_h[e * BN + w * 32 + 16 + ln]);
    const f32x4 c0 = (f32x4){bb0, bb0, bb0, bb0};
    const f32x4 c1 = (f32x4){bb1, bb1, bb1, bb1};

#pragma unroll
    for (int kc = 0; kc < 8; ++kc) {
      uint4* bc = b[kc];
      if (kc == 0) {
#pragma unroll
        for (int i = 0; i < 4; ++i) {
          acc[i][0] = __builtin_amdgcn_mfma_f32_16x16x32_bf16(
              a[i][0], *(const bf16x8*)&bc[0], c0, 0, 0, 0);
          acc[i][1] = __builtin_amdgcn_mfma_f32_16x16x32_bf16(
              a[i][0], *(const bf16x8*)&bc[1], c1, 0, 0, 0);
        }
      } else {
#pragma unroll
        for (int i = 0; i < 4; ++i)
#pragma unroll
          for (int j = 0; j < 2; ++j)
            acc[i][j] = __builtin_amdgcn_mfma_f32_16x16x32_bf16(
                a[i][kc], *(const bf16x8*)&bc[j], acc[i][j], 0, 0, 0);
      }
      if (ei < NE - 1) {  // refill slot kc with next expert's set (consumed 8 sets later)
        const uint4* p = Wf + (size_t)(en * 8 + kc) * 1024 + voff;
        bc[0] = p[0]; bc[1] = p[64];
      }
    }
    // ---- expert epilogue: gelu + gate-weighted accumulate (bias already in acc)
    {
      f32x4 gv[4];
#pragma unroll
      for (int i = 0; i < 4; ++i)
        gv[i] = *(const f32x4*)&gate_t[e * GROW + i * 16 + quad * 4];
#pragma unroll
      for (int i = 0; i < 4; ++i)
#pragma unroll
        for (int j = 0; j < 2; ++j)
#pragma unroll
          for (int r = 0; r < 4; ++r)
            oacc[i][j][r] = fmaf(gv[i][r], gelu_f(acc[i][j][r]), oacc[i][j][r]);
    }
  }

  // ---- store (each out element owned by exactly one wave)
#pragma unroll
  for (int i = 0; i < 4; ++i)
#pragma unroll
    for (int r = 0; r < 4; ++r) {
      int row = m0 + i * 16 + quad * 4 + r;
      float* orow = out + (size_t)row * NO + n0 + w * 32 + ln;
      orow[0]  = oacc[i][0][r];
      orow[16] = oacc[i][1][r];
    }
}

extern "C" void kernel_launch(void* const* d_in, const int* in_sizes, int n_in,
                              void* d_out, int out_size, void* d_ws, size_t ws_size,
                              hipStream_t stream) {
  const float* x  = (const float*)d_in[0];
  const float* We = (const float*)d_in[1];
  const float* be = (const float*)d_in[2];
  const float* Wg = (const float*)d_in[3];
  const float* bg = (const float*)d_in[4];
  float* out = (float*)d_out;
  unsigned short* Wf  = (unsigned short*)d_ws;                                      // 2 MB bf16, fragment-ordered
  unsigned short* Wgt = (unsigned short*)((char*)d_ws + (size_t)NE * NO * KD * 2);  // 8 KB bf16 [E][D]

  moe_prep<<<257, 256, 0, stream>>>(We, Wf, Wg, Wgt);
  moe_main<<<512, 256, 0, stream>>>(x, (const uint4*)Wf, Wgt, be, bg, out);
}

// Round 7
// 122.009 us; speedup vs baseline: 1.1002x; 1.1002x over previous
//
#include <hip/hip_runtime.h>
#include <stdint.h>

#define KD 256
#define NO 256
#define NE 16
#define BM 64
#define BN 128
#define XROW 264        // X stage row stride (shorts): 256 + 8 pad
#define GROW 68         // gate_t row stride (floats)

typedef short bf16x8 __attribute__((ext_vector_type(8)));
typedef float f32x4 __attribute__((ext_vector_type(4)));

__device__ __forceinline__ unsigned short f2bf(float f) {
  uint32_t u = __float_as_uint(f);
  u += 0x7fffu + ((u >> 16) & 1u);   // RNE (finite inputs)
  return (unsigned short)(u >> 16);
}
__device__ __forceinline__ float bf2f(unsigned short h) {
  return __uint_as_float(((uint32_t)h) << 16);
}
// gelu(h) = h * sigmoid(h*(1.5957691 + 0.0713548 h^2))  (tanh form)
// exp2 variant folds log2(e) into the constants (saves the __expf internal mul).
__device__ __forceinline__ float gelu_f(float h) {
#if __has_builtin(__builtin_amdgcn_exp2f)
  float zn = h * fmaf(-0.10294817f, h * h, -2.3022077f);   // -z*log2(e)
  return h * __builtin_amdgcn_rcpf(1.0f + __builtin_amdgcn_exp2f(zn));
#else
  float z = h * fmaf(0.07135481627f, h * h, 1.5957691216f);
  return h * __builtin_amdgcn_rcpf(1.0f + __expf(-z));
#endif
}

// ---- prep: We[e][d][o] -> Wf fragment-ordered bf16; Wg[d][e] -> Wgt[e][d] bf16 ----
// Wf layout: [e][kc(0..7)][ob(0..15)][lane(0..63)][i(0..7)] bf16, element =
// We[e][ kc*32 + (lane>>4)*8 + i ][ ob*16 + (lane&15) ].  (UNCHANGED — proven)
__global__ void moe_prep(const float* __restrict__ We, unsigned short* __restrict__ Wf,
                         const float* __restrict__ Wg, unsigned short* __restrict__ Wgt)
{
  __shared__ float ts[256 * 17];  // [d][o] tile, padded
  const int tid = threadIdx.x;
  const int bid = blockIdx.x;
  if (bid < 256) {
    const int e = bid >> 4, ob = bid & 15;
    const float* src = We + (size_t)e * KD * NO + ob * 16;
    const int o = tid & 15, dg = tid >> 4;
#pragma unroll
    for (int p = 0; p < 16; ++p) {
      int d = p * 16 + dg;
      ts[d * 17 + o] = src[(size_t)d * NO + o];
    }
    __syncthreads();
    const int w = tid >> 6, l = tid & 63;
    const int q = l >> 4, ln = l & 15;
#pragma unroll
    for (int kk = 0; kk < 2; ++kk) {
      int kc = w + kk * 4;
      unsigned int pk[4];
#pragma unroll
      for (int h = 0; h < 4; ++h) {
        unsigned short lo = f2bf(ts[(kc * 32 + q * 8 + h * 2 + 0) * 17 + ln]);
        unsigned short hi = f2bf(ts[(kc * 32 + q * 8 + h * 2 + 1) * 17 + ln]);
        pk[h] = (unsigned int)lo | ((unsigned int)hi << 16);
      }
      uint4* dst = (uint4*)(Wf + ((((size_t)(e * 8 + kc) * 16 + ob) * 64) + l) * 8);
      *dst = make_uint4(pk[0], pk[1], pk[2], pk[3]);
    }
  } else {
    int d = tid;
    const float* wr = Wg + (size_t)d * NE;
#pragma unroll
    for (int e = 0; e < NE; ++e)
      Wgt[e * KD + d] = f2bf(wr[e]);
  }
}

// ---- main: R5 structure + per-wave expert stagger (break SIMD phase-lock) ----
__launch_bounds__(256, 2)
__global__ void moe_main(const float* __restrict__ x,
                         const uint4* __restrict__ Wf,
                         const unsigned short* __restrict__ Wgt,
                         const float* __restrict__ be,
                         const float* __restrict__ bg,
                         float* __restrict__ out)
{
  __shared__ __align__(16) unsigned short Xs[BM * XROW];  // 33792 B
  __shared__ __align__(16) float gate_t[NE * GROW];        // 4352 B
  __shared__ unsigned short be_h[NE * BN];                 // 4096 B

  const int tid = threadIdx.x;
  const int bid = blockIdx.x;
  const int half = bid & 1;
  const int n0 = half * BN;
  const int m0 = (bid >> 1) * BM;
  const int w = tid >> 6, lane = tid & 63;   // wave w owns cols w*32..w*32+31 (disjoint B)
  const int ln = lane & 15, quad = lane >> 4;
  // per-wave expert rotation, scalarized so refill addresses stay SGPR-based
  const int eoff = __builtin_amdgcn_readfirstlane(((tid >> 6) * 4 + bid) & 15);

  // per-wave fragment offset (uint4 units); frag j at +j*64 (=1024 B imm)
  const int voff = (half * 8 + w * 2) * 64 + lane;

  // ---- stage X tile fp32 -> bf16
  {
    const float4* xg = (const float4*)x + (size_t)m0 * (KD / 4);
#pragma unroll
    for (int p = 0; p < 16; ++p) {
      int idx = p * 256 + tid;
      int r = idx >> 6, c = idx & 63;
      float4 v = xg[r * (KD / 4) + c];
      uint32_t lo = (uint32_t)f2bf(v.x) | ((uint32_t)f2bf(v.y) << 16);
      uint32_t hi = (uint32_t)f2bf(v.z) | ((uint32_t)f2bf(v.w) << 16);
      *(uint2*)&Xs[r * XROW + c * 4] = make_uint2(lo, hi);
    }
  }
  // ---- ring fill: sets 0..3 of rotated sequence = expert eoff, kc 0..3
  uint4 b[4][2];
#pragma unroll
  for (int kc = 0; kc < 4; ++kc) {
    const uint4* p = Wf + ((size_t)eoff * 8 + kc) * 1024 + voff;
    b[kc][0] = p[0]; b[kc][1] = p[64];
  }
  // ---- stage bias (bf16; |be|<=1/16 -> error ~1e-4)
#pragma unroll
  for (int p = 0; p < 8; ++p) {
    int idx = p * 256 + tid;
    int e = idx >> 7, c = idx & 127;
    be_h[e * BN + c] = f2bf(be[e * NO + n0 + c]);
  }
  __syncthreads();

  // ---- A fragments, FULL tile (64 rows x K=256): 32 frags, loaded ONCE (live in AGPRs)
  bf16x8 a[4][8];
#pragma unroll
  for (int i = 0; i < 4; ++i)
#pragma unroll
    for (int kc = 0; kc < 8; ++kc)
      a[i][kc] = *(const bf16x8*)&Xs[(i * 16 + ln) * XROW + kc * 32 + quad * 8];

  // ---- gate: wave w computes rows w*16..w*16+15 for all 16 experts (lane ln = expert)
  {
    f32x4 g = {0.f, 0.f, 0.f, 0.f};
#pragma unroll
    for (int kc = 0; kc < 8; ++kc) {
      bf16x8 af = *(const bf16x8*)&Xs[(w * 16 + ln) * XROW + kc * 32 + quad * 8];
      bf16x8 wb = *(const bf16x8*)(Wgt + (size_t)ln * KD + kc * 32 + quad * 8);
      g = __builtin_amdgcn_mfma_f32_16x16x32_bf16(af, wb, g, 0, 0, 0);
    }
    float bgl = bg[ln];
#pragma unroll
    for (int r = 0; r < 4; ++r) {
      float v = g[r] + bgl;
      float mx = v;
#pragma unroll
      for (int msk = 1; msk < 16; msk <<= 1)
        mx = fmaxf(mx, __shfl_xor(mx, msk, 64));
      float ev = __expf(v - mx);
      float s = ev;
#pragma unroll
      for (int msk = 1; msk < 16; msk <<= 1)
        s += __shfl_xor(s, msk, 64);
      gate_t[ln * GROW + w * 16 + quad * 4 + r] = ev * __builtin_amdgcn_rcpf(s);
    }
  }
  __syncthreads();  // gate_t visible; last barrier in the kernel

  f32x4 acc[4][2], oacc[4][2];
#pragma unroll
  for (int i = 0; i < 4; ++i)
#pragma unroll
    for (int j = 0; j < 2; ++j) {
      acc[i][j] = (f32x4){0.f, 0.f, 0.f, 0.f};
      oacc[i][j] = (f32x4){0.f, 0.f, 0.f, 0.f};
    }

#pragma unroll 1
  for (int ei = 0; ei < NE; ++ei) {
    const int e  = (eoff + ei) & 15;        // this wave's current expert (scalar)
    const int en = (eoff + ei + 1) & 15;    // next expert (scalar)
    const uint4* bse = Wf + (size_t)e  * 8192 + voff;
    const uint4* bsn = Wf + (size_t)en * 8192 + voff;

#pragma unroll
    for (int kc = 0; kc < 8; ++kc) {
      uint4* bc = b[kc & 3];
#pragma unroll
      for (int i = 0; i < 4; ++i)
#pragma unroll
        for (int j = 0; j < 2; ++j)
          acc[i][j] = __builtin_amdgcn_mfma_f32_16x16x32_bf16(
              a[i][kc], *(const bf16x8*)&bc[j], acc[i][j], 0, 0, 0);
      // refill the slot just consumed with set 4 ahead
      if (kc < 4) {
        const uint4* p = bse + (kc + 4) * 1024;
        bc[0] = p[0]; bc[1] = p[64];
      } else if (ei < NE - 1) {
        const uint4* p = bsn + (kc - 4) * 1024;
        bc[0] = p[0]; bc[1] = p[64];
      }
    }
    // ---- expert epilogue: bias + gelu + gate-weighted accumulate
    {
      f32x4 gv[4];
#pragma unroll
      for (int i = 0; i < 4; ++i)
        gv[i] = *(const f32x4*)&gate_t[e * GROW + i * 16 + quad * 4];
      const float bb0 = bf2f(be_h[e * BN + w * 32 + ln]);
      const float bb1 = bf2f(be_h[e * BN + w * 32 + 16 + ln]);
#pragma unroll
      for (int i = 0; i < 4; ++i)
#pragma unroll
        for (int j = 0; j < 2; ++j)
#pragma unroll
          for (int r = 0; r < 4; ++r) {
            float hh = acc[i][j][r] + (j ? bb1 : bb0);
            oacc[i][j][r] = fmaf(gv[i][r], gelu_f(hh), oacc[i][j][r]);
            acc[i][j][r] = 0.f;
          }
    }
  }

  // ---- store (each out element owned by exactly one wave)
#pragma unroll
  for (int i = 0; i < 4; ++i)
#pragma unroll
    for (int r = 0; r < 4; ++r) {
      int row = m0 + i * 16 + quad * 4 + r;
      float* orow = out + (size_t)row * NO + n0 + w * 32 + ln;
      orow[0]  = oacc[i][0][r];
      orow[16] = oacc[i][1][r];
    }
}

extern "C" void kernel_launch(void* const* d_in, const int* in_sizes, int n_in,
                              void* d_out, int out_size, void* d_ws, size_t ws_size,
                              hipStream_t stream) {
  const float* x  = (const float*)d_in[0];
  const float* We = (const float*)d_in[1];
  const float* be = (const float*)d_in[2];
  const float* Wg = (const float*)d_in[3];
  const float* bg = (const float*)d_in[4];
  float* out = (float*)d_out;
  unsigned short* Wf  = (unsigned short*)d_ws;                                      // 2 MB bf16, fragment-ordered
  unsigned short* Wgt = (unsigned short*)((char*)d_ws + (size_t)NE * NO * KD * 2);  // 8 KB bf16 [E][D]

  moe_prep<<<257, 256, 0, stream>>>(We, Wf, Wg, Wgt);
  moe_main<<<512, 256, 0, stream>>>(x, (const uint4*)Wf, Wgt, be, bg, out);
}